// Round 1
// baseline (52.516 us; speedup 1.0000x reference)
//
#include <hip/hip_runtime.h>

#define B_ 16
#define C_ 12
#define H_ 384
#define W_ 384
#define LK 96
#define NTHR 256
#define NBLK 2304   // = B_*H_*(W_/4) / NTHR exactly (589824 groups)
#define NTOT ((double)(B_ * C_ * H_ * W_))

__device__ __forceinline__ float mask_w(float v) {
    // Sequential masking collapses to 3 compares (1.0,2.0 both < T2 so they
    // get overwritten by 5.0 on the third pass).
    const float T2 = (133.0f - 33.44f) / 47.54f;  // 2.09424
    const float T3 = (181.0f - 33.44f) / 47.54f;  // 3.10383
    const float T4 = (255.0f - 33.44f) / 47.54f;  // 4.66050
    return v < T2 ? 5.0f : (v < T3 ? 10.0f : (v < T4 ? 30.0f : v));
}

__global__ __launch_bounds__(NTHR) void loss_main(
    const float* __restrict__ y_pre, const float* __restrict__ y_true,
    const float* __restrict__ x_l, const float* __restrict__ wlk,
    double* __restrict__ partial)
{
    const int g = blockIdx.x * NTHR + threadIdx.x;   // group id, exact fit
    const int j   = g % (W_ / 4);                    // w-group (4 px wide)
    const int tmp = g / (W_ / 4);
    const int h   = tmp % H_;
    const int b   = tmp / H_;

    // --- bilinear setup (half-pixel, scale 4, clamped == jax renorm) ---
    const float src_h = h * 0.25f - 0.375f;
    const float kf = floorf(src_h);
    const float fh = src_h - kf;
    const int k0 = max((int)kf, 0);
    const int k1 = min((int)kf + 1, LK - 1);
    const int jm1 = max(j - 1, 0);
    const int jp1 = min(j + 1, LK - 1);

    const size_t pix  = (size_t)h * W_ + (size_t)j * 4;  // within-batch pixel
    const float4 x4 = *(const float4*)(x_l + (size_t)b * H_ * W_ + pix);
    const float xv[4] = {x4.x, x4.y, x4.z, x4.w};

    const size_t ybase  = (size_t)b * C_ * H_ * W_ + pix;
    const size_t lkbase = (size_t)b * C_ * LK * LK;

    float s[4] = {0.f, 0.f, 0.f, 0.f};  // excl cumsum of |y_true_c - x|
    float t[4] = {0.f, 0.f, 0.f, 0.f};  // excl cumsum of bilinear(w_LK_c)
    float acc = 0.f;

    #pragma unroll
    for (int c = 0; c < C_; ++c) {
        const float4 yt4 = *(const float4*)(y_true + ybase + (size_t)c * H_ * W_);
        const float4 yp4 = *(const float4*)(y_pre  + ybase + (size_t)c * H_ * W_);
        const float* Lc = wlk + lkbase + (size_t)c * LK * LK;

        // 6 taps: rows k0,k1 x cols jm1,j,jp1 (shared by the 4 pixels)
        const float c0 = Lc[k0 * LK + jm1], c1 = Lc[k0 * LK + j], c2 = Lc[k0 * LK + jp1];
        const float d0 = Lc[k1 * LK + jm1], d1 = Lc[k1 * LK + j], d2 = Lc[k1 * LK + jp1];
        const float e0 = c0 + fh * (d0 - c0);
        const float e1 = c1 + fh * (d1 - c1);
        const float e2 = c2 + fh * (d2 - c2);
        // per-pixel horizontal weights: r=0:(0.375,0.625) r=1:(0.125,0.875)
        //                               r=2:(0.875,0.125) r=3:(0.625,0.375)
        float bil[4];
        bil[0] = 0.375f * e0 + 0.625f * e1;
        bil[1] = 0.125f * e0 + 0.875f * e1;
        bil[2] = 0.875f * e1 + 0.125f * e2;
        bil[3] = 0.625f * e1 + 0.375f * e2;

        const float yt[4] = {yt4.x, yt4.y, yt4.z, yt4.w};
        const float yp[4] = {yp4.x, yp4.y, yp4.z, yp4.w};
        #pragma unroll
        for (int r = 0; r < 4; ++r) {
            const float wt = mask_w(yt[r]);
            acc += (wt + s[r] + t[r]) * fabsf(yp[r] - yt[r]);
            s[r] += fabsf(yt[r] - xv[r]);
            t[r] += bil[r];
        }
    }

    // --- block reduction (double) ---
    double v = (double)acc;
    #pragma unroll
    for (int off = 32; off > 0; off >>= 1) v += __shfl_down(v, off, 64);
    __shared__ double lds[NTHR / 64];
    const int lane = threadIdx.x & 63, wid = threadIdx.x >> 6;
    if (lane == 0) lds[wid] = v;
    __syncthreads();
    if (threadIdx.x == 0)
        partial[blockIdx.x] = lds[0] + lds[1] + lds[2] + lds[3];
}

__global__ __launch_bounds__(256) void loss_final(
    const double* __restrict__ partial, float* __restrict__ out)
{
    double v = 0.0;
    for (int i = threadIdx.x; i < NBLK; i += 256) v += partial[i];
    #pragma unroll
    for (int off = 32; off > 0; off >>= 1) v += __shfl_down(v, off, 64);
    __shared__ double lds[4];
    const int lane = threadIdx.x & 63, wid = threadIdx.x >> 6;
    if (lane == 0) lds[wid] = v;
    __syncthreads();
    if (threadIdx.x == 0)
        out[0] = (float)((lds[0] + lds[1] + lds[2] + lds[3]) / NTOT);
}

extern "C" void kernel_launch(void* const* d_in, const int* in_sizes, int n_in,
                              void* d_out, int out_size, void* d_ws, size_t ws_size,
                              hipStream_t stream) {
    const float* y_pre  = (const float*)d_in[0];
    const float* y_true = (const float*)d_in[1];
    const float* x_l    = (const float*)d_in[2];
    const float* wlk    = (const float*)d_in[3];
    double* partial = (double*)d_ws;   // needs NBLK*8 = 18432 bytes

    loss_main<<<NBLK, NTHR, 0, stream>>>(y_pre, y_true, x_l, wlk, partial);
    loss_final<<<1, 256, 0, stream>>>(partial, (float*)d_out);
}